// Round 1
// baseline (531.106 us; speedup 1.0000x reference)
//
#include <hip/hip_runtime.h>

// RGCN layer, MI355X. Pipeline:
//   ws layout: A[N][768] bf16 (C0|C1|x), Bt[256][768] bf16, deg4[4][N] int,
//              cnt[N] int, edgebuf[N][64] int  -> 181.6 MB total
//   K1 build_edges: per-rel degree histogram + bucket edges by dst (src|rel packed)
//   K2 build_bt:    Bt[n][k] bf16 from bases/loop_weight (transposed for MFMA B-frag)
//   K3 conv_x:      x fp32 -> bf16 into A cols [512,768)
//   K4 agg_edges:   one wave per dst: C_b[d] = sum_e w_comp[r,b]/deg_r[d] * x[src]
//   K5 gemm_ln:     [N,768]x[768,256] bf16 MFMA 32x32x16 + bias + LayerNorm + ReLU

#define NN 100000
#define NR 4
#define NE 200000
#define KDIM 768
#define CAP 64

typedef __attribute__((ext_vector_type(8))) short short8;
typedef __attribute__((ext_vector_type(16))) float floatx16;

__device__ __forceinline__ unsigned short f2bf(float f) {
  unsigned u = __float_as_uint(f);
  u += 0x7FFFu + ((u >> 16) & 1u);
  return (unsigned short)(u >> 16);
}

// ---------------- K1: degree histogram + edge bucketing ----------------
__global__ void build_edges(const int* __restrict__ src, const int* __restrict__ dst,
                            int* __restrict__ deg4, int* __restrict__ cnt,
                            int* __restrict__ edgebuf) {
  int i = blockIdx.x * 256 + threadIdx.x;
  if (i >= NR * NE) return;
  int r = i / NE;            // relation id (compiler magic-div)
  int s = src[i];
  int d = dst[i];
  atomicAdd(&deg4[r * NN + d], 1);
  int pos = atomicAdd(&cnt[d], 1);
  if (pos < CAP) edgebuf[d * CAP + pos] = s | (r << 20);  // src<2^17, rel in bits 20-21
}

// ---------------- K2: build B^T (bf16) ----------------
// Bt[n][k]: k in [0,256) -> bases[0][k][n]; [256,512) -> bases[1][k-256][n];
//           [512,768) -> loop_w[k-512][n]
__global__ void build_bt(const float* __restrict__ bases, const float* __restrict__ loop_w,
                         unsigned short* __restrict__ Bt) {
  int i = blockIdx.x * 256 + threadIdx.x;  // 768*256 = 196608 exact
  int n = i & 255;
  int k = i >> 8;
  float v;
  if (k < 256)      v = bases[k * 256 + n];
  else if (k < 512) v = bases[65536 + (k - 256) * 256 + n];
  else              v = loop_w[(k - 512) * 256 + n];
  Bt[(size_t)n * KDIM + k] = f2bf(v);
}

// ---------------- K3: x -> bf16 into A[:, 512:768] ----------------
__global__ void conv_x(const float* __restrict__ x, unsigned short* __restrict__ A) {
  int q = blockIdx.x * 256 + threadIdx.x;  // NN*64 quads exact (25000 blocks)
  int row = q >> 6;
  int c4 = (q & 63) << 2;
  const float4 v = *(const float4*)(x + (size_t)row * 256 + c4);
  ushort4 u;
  u.x = f2bf(v.x); u.y = f2bf(v.y); u.z = f2bf(v.z); u.w = f2bf(v.w);
  *(ushort4*)(A + (size_t)row * KDIM + 512 + c4) = u;
}

// ---------------- K4: aggregation, one wave per dst node ----------------
__global__ void agg_edges(const float* __restrict__ x, const int* __restrict__ edgebuf,
                          const int* __restrict__ cnt, const int* __restrict__ deg4,
                          const float* __restrict__ w_comp, unsigned short* __restrict__ A) {
  int wave = threadIdx.x >> 6;
  int lane = threadIdx.x & 63;
  int d = blockIdx.x * 4 + wave;  // grid 25000*4 = 100000 exact
  float s0[NR], s1[NR];
#pragma unroll
  for (int r = 0; r < NR; ++r) {
    float dg = (float)deg4[r * NN + d];
    float inv = 1.0f / fmaxf(dg, 1.0f);
    s0[r] = w_comp[2 * r] * inv;
    s1[r] = w_comp[2 * r + 1] * inv;
  }
  int c = cnt[d]; c = c < CAP ? c : CAP;
  const int* eb = edgebuf + d * CAP;
  float4 a0 = make_float4(0.f, 0.f, 0.f, 0.f);
  float4 a1 = make_float4(0.f, 0.f, 0.f, 0.f);
  for (int i = 0; i < c; ++i) {
    int v = eb[i];                     // wave-uniform broadcast load
    int s = v & 0xFFFFF;
    int r = v >> 20;
    const float4 xv = *(const float4*)(x + (size_t)s * 256 + lane * 4);
    float w0 = s0[r], w1 = s1[r];
    a0.x += w0 * xv.x; a0.y += w0 * xv.y; a0.z += w0 * xv.z; a0.w += w0 * xv.w;
    a1.x += w1 * xv.x; a1.y += w1 * xv.y; a1.z += w1 * xv.z; a1.w += w1 * xv.w;
  }
  ushort4 u0, u1;
  u0.x = f2bf(a0.x); u0.y = f2bf(a0.y); u0.z = f2bf(a0.z); u0.w = f2bf(a0.w);
  u1.x = f2bf(a1.x); u1.y = f2bf(a1.y); u1.z = f2bf(a1.z); u1.w = f2bf(a1.w);
  *(ushort4*)(A + (size_t)d * KDIM + lane * 4) = u0;
  *(ushort4*)(A + (size_t)d * KDIM + 256 + lane * 4) = u1;
}

// ---------------- K5: GEMM [N,768]x[768,256] bf16 MFMA + bias + LN + ReLU ----------------
// Block: 256 thr (4 waves), tile M=128 x N=256, K staged in BK=32 chunks.
// Wave w computes rows [32w,32w+32) x all 256 cols (8 MFMA 32x32 tiles) so
// LayerNorm stats live inside the wave (shfl_xor over 32-lane halves).
#define BM 128
#define LDA 40  // bf16 elems; 80 B row stride -> 16B-aligned, conflict-free groups
#define LDB 40
__launch_bounds__(256, 2)
__global__ void gemm_ln(const unsigned short* __restrict__ A, const unsigned short* __restrict__ Bt,
                        const float* __restrict__ h_bias, const float* __restrict__ gamma,
                        const float* __restrict__ beta, float* __restrict__ out) {
  __shared__ unsigned short As[BM * LDA];
  __shared__ unsigned short Bs[256 * LDB];
  const int tid = threadIdx.x;
  const int wave = tid >> 6;
  const int lane = tid & 63;
  const int m0 = blockIdx.x * BM;
  const int l31 = lane & 31;
  const int half = lane >> 5;

  floatx16 acc[8];
#pragma unroll
  for (int t = 0; t < 8; ++t)
#pragma unroll
    for (int r = 0; r < 16; ++r) acc[t][r] = 0.0f;

  const int srow = tid >> 2;        // 0..63 staging row
  const int sq = (tid & 3) * 8;     // k-element offset (16B)

  for (int k0 = 0; k0 < KDIM; k0 += 32) {
    // stage A: 128 rows x 32 k (guarded past N)
#pragma unroll
    for (int p = 0; p < 2; ++p) {
      int r = srow + p * 64;
      int gr = m0 + r;
      uint4 v = make_uint4(0u, 0u, 0u, 0u);
      if (gr < NN) v = *(const uint4*)(A + (size_t)gr * KDIM + k0 + sq);
      *(uint4*)(&As[r * LDA + sq]) = v;
    }
    // stage B^T: 256 rows x 32 k
#pragma unroll
    for (int p = 0; p < 4; ++p) {
      int n = srow + p * 64;
      uint4 v = *(const uint4*)(Bt + (size_t)n * KDIM + k0 + sq);
      *(uint4*)(&Bs[n * LDB + sq]) = v;
    }
    __syncthreads();
#pragma unroll
    for (int kk = 0; kk < 2; ++kk) {
      // A-frag: m = lane&31 (wave's row), k = half*8 + j
      short8 af = *(const short8*)(&As[(wave * 32 + l31) * LDA + kk * 16 + half * 8]);
#pragma unroll
      for (int t = 0; t < 8; ++t) {
        short8 bfg = *(const short8*)(&Bs[(t * 32 + l31) * LDB + kk * 16 + half * 8]);
        acc[t] = __builtin_amdgcn_mfma_f32_32x32x16_bf16(af, bfg, acc[t], 0, 0, 0);
      }
    }
    __syncthreads();
  }

  // epilogue: bias, LayerNorm over 256 cols, gamma/beta, ReLU
  float bcol[8], gc[8], bc[8];
#pragma unroll
  for (int t = 0; t < 8; ++t) {
    int col = t * 32 + l31;
    bcol[t] = h_bias[col];
    gc[t] = gamma[col];
    bc[t] = beta[col];
  }
#pragma unroll
  for (int t = 0; t < 8; ++t)
#pragma unroll
    for (int r = 0; r < 16; ++r) acc[t][r] += bcol[t];

  const int m_base = m0 + wave * 32;
#pragma unroll
  for (int r = 0; r < 16; ++r) {
    float s = 0.f, q = 0.f;
#pragma unroll
    for (int t = 0; t < 8; ++t) { float v = acc[t][r]; s += v; q += v * v; }
#pragma unroll
    for (int m = 16; m >= 1; m >>= 1) {  // reduce within 32-lane half
      s += __shfl_xor(s, m);
      q += __shfl_xor(q, m);
    }
    float mean = s * (1.0f / 256.0f);
    float var = q * (1.0f / 256.0f) - mean * mean;
    float rstd = rsqrtf(var + 1e-5f);
    int row = (r & 3) + ((r >> 2) << 3) + (half << 2);  // C/D layout, 32x32
    int grow = m_base + row;
    if (grow < NN) {
#pragma unroll
      for (int t = 0; t < 8; ++t) {
        float v = (acc[t][r] - mean) * rstd * gc[t] + bc[t];
        out[(size_t)grow * 256 + t * 32 + l31] = fmaxf(v, 0.0f);
      }
    }
  }
}

extern "C" void kernel_launch(void* const* d_in, const int* in_sizes, int n_in,
                              void* d_out, int out_size, void* d_ws, size_t ws_size,
                              hipStream_t stream) {
  const float* x      = (const float*)d_in[0];
  const int*   src    = (const int*)d_in[1];
  const int*   dst    = (const int*)d_in[2];
  const float* bases  = (const float*)d_in[3];
  const float* w_comp = (const float*)d_in[4];
  const float* loop_w = (const float*)d_in[5];
  const float* h_bias = (const float*)d_in[6];
  const float* gamma  = (const float*)d_in[7];
  const float* beta   = (const float*)d_in[8];
  float* out = (float*)d_out;

  char* ws = (char*)d_ws;
  unsigned short* A  = (unsigned short*)ws;                       // 153,600,000 B
  unsigned short* Bt = (unsigned short*)(ws + 153600000);         //     393,216 B
  int* deg4    = (int*)(ws + 153993216);                          //   1,600,000 B
  int* cnt     = (int*)(ws + 155593216);                          //     400,000 B
  int* edgebuf = (int*)(ws + 155993216);                          //  25,600,000 B
  // total 181,593,216 B

  hipMemsetAsync(deg4, 0, 2000000, stream);  // deg4 + cnt contiguous

  build_edges<<<(NR * NE + 255) / 256, 256, 0, stream>>>(src, dst, deg4, cnt, edgebuf);
  build_bt<<<768, 256, 0, stream>>>(bases, loop_w, Bt);
  conv_x<<<25000, 256, 0, stream>>>(x, A);
  agg_edges<<<25000, 256, 0, stream>>>(x, edgebuf, cnt, deg4, w_comp, A);
  gemm_ln<<<(NN + BM - 1) / BM, 256, 0, stream>>>(A, Bt, h_bias, gamma, beta, out);
}

// Round 2
// 403.696 us; speedup vs baseline: 1.3156x; 1.3156x over previous
//
#include <hip/hip_runtime.h>

// RGCN layer, MI355X. Pipeline (round 2):
//   ws: A[N][768] bf16 (C0|C1|Xbf), Bt[256][768] bf16, cnt[N] int, edgebuf[N][64] int
//   K1 build_edges: bucket edges by dst (src|rel packed), ONE atomic per edge
//   K2 build_bt:    Bt[n][k] bf16 (transposed B for MFMA B-frag)
//   K3 conv_x:      x fp32 -> bf16 into A cols [512,768)
//   K4 agg_edges:   one wave per dst; deg via ballot over bucketed words;
//                   bf16 gathers (halved bytes), shfl-prefetched edges, 4x unroll
//   K5 gemm_ln:     [N,768]x[768,256] MFMA 32x32x16, global_load_lds(16B) staging,
//                   XOR-swizzled LDS, fused bias+LayerNorm+ReLU

#define NN 100000
#define NR 4
#define NE 200000
#define KDIM 768
#define CAP 64

typedef __attribute__((ext_vector_type(8))) short short8;
typedef __attribute__((ext_vector_type(16))) float floatx16;

__device__ __forceinline__ unsigned short f2bf(float f) {
  unsigned u = __float_as_uint(f);
  u += 0x7FFFu + ((u >> 16) & 1u);
  return (unsigned short)(u >> 16);
}

__device__ __forceinline__ void gload16(const unsigned short* g, unsigned short* l) {
  __builtin_amdgcn_global_load_lds(
      (const __attribute__((address_space(1))) unsigned int*)g,
      (__attribute__((address_space(3))) unsigned int*)l, 16, 0, 0);
}

// ---------------- K1: edge bucketing (one atomic per edge) ----------------
__global__ void build_edges(const int* __restrict__ src, const int* __restrict__ dst,
                            int* __restrict__ cnt, int* __restrict__ edgebuf) {
  int i = blockIdx.x * 256 + threadIdx.x;
  if (i >= NR * NE) return;
  int r = i / NE;
  int s = src[i];
  int d = dst[i];
  int pos = atomicAdd(&cnt[d], 1);
  if (pos < CAP) edgebuf[d * CAP + pos] = s | (r << 20);  // src<2^17, rel bits 20-21
}

// ---------------- K2: build B^T (bf16) ----------------
__global__ void build_bt(const float* __restrict__ bases, const float* __restrict__ loop_w,
                         unsigned short* __restrict__ Bt) {
  int i = blockIdx.x * 256 + threadIdx.x;  // 768*256 exact
  int n = i & 255;
  int k = i >> 8;
  float v;
  if (k < 256)      v = bases[k * 256 + n];
  else if (k < 512) v = bases[65536 + (k - 256) * 256 + n];
  else              v = loop_w[(k - 512) * 256 + n];
  Bt[(size_t)n * KDIM + k] = f2bf(v);
}

// ---------------- K3: x -> bf16 into A[:, 512:768] ----------------
__global__ void conv_x(const float* __restrict__ x, unsigned short* __restrict__ A) {
  int q = blockIdx.x * 256 + threadIdx.x;  // 25000 blocks exact
  int row = q >> 6;
  int c4 = (q & 63) << 2;
  const float4 v = *(const float4*)(x + (size_t)row * 256 + c4);
  ushort4 u;
  u.x = f2bf(v.x); u.y = f2bf(v.y); u.z = f2bf(v.z); u.w = f2bf(v.w);
  *(ushort4*)(A + (size_t)row * KDIM + 512 + c4) = u;
}

// ---------------- K4: aggregation, one wave per dst, bf16 gathers ----------------
__global__ void agg_edges(const int* __restrict__ edgebuf, const int* __restrict__ cnt,
                          const float* __restrict__ w_comp, unsigned short* __restrict__ A) {
  const int wave = threadIdx.x >> 6;
  const int lane = threadIdx.x & 63;
  const int d = blockIdx.x * 4 + wave;  // 25000*4 = 100000 exact

  int c = cnt[d]; c = c < CAP ? c : CAP;
  int ev = 0;
  if (lane < c) ev = edgebuf[d * CAP + lane];  // coalesced prefetch of the bucket
  const int rl = ev >> 20;

  // per-relation degree from the bucketed words (replaces deg4 atomics)
  float s00, s01, s02, s03, s10, s11, s12, s13;
  {
    float d0 = (float)__popcll(__ballot(lane < c && rl == 0));
    float d1 = (float)__popcll(__ballot(lane < c && rl == 1));
    float d2 = (float)__popcll(__ballot(lane < c && rl == 2));
    float d3 = (float)__popcll(__ballot(lane < c && rl == 3));
    float i0 = 1.0f / fmaxf(d0, 1.0f), i1 = 1.0f / fmaxf(d1, 1.0f);
    float i2 = 1.0f / fmaxf(d2, 1.0f), i3 = 1.0f / fmaxf(d3, 1.0f);
    s00 = w_comp[0] * i0; s10 = w_comp[1] * i0;
    s01 = w_comp[2] * i1; s11 = w_comp[3] * i1;
    s02 = w_comp[4] * i2; s12 = w_comp[5] * i2;
    s03 = w_comp[6] * i3; s13 = w_comp[7] * i3;
  }

  float a0[4] = {0.f, 0.f, 0.f, 0.f};
  float a1[4] = {0.f, 0.f, 0.f, 0.f};
  const unsigned short* Xl = A + 512 + lane * 4;  // bf16 x panel, this lane's 4 cols

#define EDGE_W(v, w0, w1)                                            \
  int r_##w0 = (v) >> 20;                                            \
  float w0 = r_##w0 < 2 ? (r_##w0 == 0 ? s00 : s01)                  \
                        : (r_##w0 == 2 ? s02 : s03);                 \
  float w1 = r_##w0 < 2 ? (r_##w0 == 0 ? s10 : s11)                  \
                        : (r_##w0 == 2 ? s12 : s13);

#define ACCUM(g, w0, w1)                                             \
  {                                                                  \
    float e0 = __uint_as_float((g).x << 16);                         \
    float e1 = __uint_as_float((g).x & 0xFFFF0000u);                 \
    float e2 = __uint_as_float((g).y << 16);                         \
    float e3 = __uint_as_float((g).y & 0xFFFF0000u);                 \
    a0[0] += (w0) * e0; a0[1] += (w0) * e1;                          \
    a0[2] += (w0) * e2; a0[3] += (w0) * e3;                          \
    a1[0] += (w1) * e0; a1[1] += (w1) * e1;                          \
    a1[2] += (w1) * e2; a1[3] += (w1) * e3;                          \
  }

  int i = 0;
  for (; i + 4 <= c; i += 4) {
    int v0 = __shfl(ev, i);
    int v1 = __shfl(ev, i + 1);
    int v2 = __shfl(ev, i + 2);
    int v3 = __shfl(ev, i + 3);
    const uint2 g0 = *(const uint2*)(Xl + (size_t)(v0 & 0xFFFFF) * KDIM);
    const uint2 g1 = *(const uint2*)(Xl + (size_t)(v1 & 0xFFFFF) * KDIM);
    const uint2 g2 = *(const uint2*)(Xl + (size_t)(v2 & 0xFFFFF) * KDIM);
    const uint2 g3 = *(const uint2*)(Xl + (size_t)(v3 & 0xFFFFF) * KDIM);
    { EDGE_W(v0, w0a, w1a) ACCUM(g0, w0a, w1a) }
    { EDGE_W(v1, w0b, w1b) ACCUM(g1, w0b, w1b) }
    { EDGE_W(v2, w0c, w1c) ACCUM(g2, w0c, w1c) }
    { EDGE_W(v3, w0d, w1d) ACCUM(g3, w0d, w1d) }
  }
  for (; i < c; ++i) {
    int v = __shfl(ev, i);
    const uint2 g = *(const uint2*)(Xl + (size_t)(v & 0xFFFFF) * KDIM);
    EDGE_W(v, w0, w1)
    ACCUM(g, w0, w1)
  }

  ushort4 u0, u1;
  u0.x = f2bf(a0[0]); u0.y = f2bf(a0[1]); u0.z = f2bf(a0[2]); u0.w = f2bf(a0[3]);
  u1.x = f2bf(a1[0]); u1.y = f2bf(a1[1]); u1.z = f2bf(a1[2]); u1.w = f2bf(a1[3]);
  *(ushort4*)(A + (size_t)d * KDIM + lane * 4) = u0;
  *(ushort4*)(A + (size_t)d * KDIM + 256 + lane * 4) = u1;
}

// ---------------- K5: GEMM + bias + LN + ReLU ----------------
// Tile M=128 x N=256, BK=32. Staging via global_load_lds(16B), LDS rows 64B
// (unpadded, as required by the lane-contiguous LDS dest), XOR chunk swizzle
// pc = c ^ ((row>>1)&3) -> ds_read_b128 at the data-BW floor (no avoidable
// conflicts). Wave owns 32 rows x 256 cols so LN reduces via shfl_xor.
#define BM 128
__launch_bounds__(256, 2)
__global__ void gemm_ln(const unsigned short* __restrict__ A, const unsigned short* __restrict__ Bt,
                        const float* __restrict__ h_bias, const float* __restrict__ gamma,
                        const float* __restrict__ beta, float* __restrict__ out) {
  __shared__ unsigned short As[BM * 32];   //  8 KB
  __shared__ unsigned short Bs[256 * 32];  // 16 KB
  const int tid = threadIdx.x;
  const int wave = tid >> 6;
  const int lane = tid & 63;
  const int l31 = lane & 31;
  const int half = lane >> 5;
  const int m0 = blockIdx.x * BM;

  floatx16 acc[8];
#pragma unroll
  for (int t = 0; t < 8; ++t)
#pragma unroll
    for (int r = 0; r < 16; ++r) acc[t][r] = 0.0f;

  // staging addresses: wave-op covers 16 rows (16 x 64B = 1KB = 64 lanes x 16B)
  // lane -> prow = rb + (lane>>2), pchunk = lane&3; global chunk lc = pchunk ^ ((prow>>1)&3)
  const int prow = 16 * wave + (lane >> 2);
  const int lc = (lane & 3) ^ ((prow >> 1) & 3);
  const unsigned short* gA = A + (size_t)(m0 + prow) * KDIM + lc * 8;
  const unsigned short* gB = Bt + (size_t)prow * KDIM + lc * 8;
  unsigned short* lA = As + 16 * wave * 32 + lane * 8;
  unsigned short* lB = Bs + 16 * wave * 32 + lane * 8;

  const int sw = (l31 >> 1) & 3;       // reader swizzle key (same for A and B rows)
  const int rA32 = (wave * 32 + l31) * 32;

  for (int k0 = 0; k0 < KDIM; k0 += 32) {
    gload16(gA, lA);
    gload16(gA + 64 * KDIM, lA + 64 * 32);
    gload16(gB, lB);
    gload16(gB + 64 * KDIM, lB + 64 * 32);
    gload16(gB + 128 * KDIM, lB + 128 * 32);
    gload16(gB + 192 * KDIM, lB + 192 * 32);
    gA += 32;
    gB += 32;
    __syncthreads();
#pragma unroll
    for (int kk = 0; kk < 2; ++kk) {
      const int pc = ((kk * 2 + half) ^ sw) * 8;
      short8 af = *(const short8*)(&As[rA32 + pc]);
#pragma unroll
      for (int t = 0; t < 8; ++t) {
        short8 bfr = *(const short8*)(&Bs[(t * 32 + l31) * 32 + pc]);
        acc[t] = __builtin_amdgcn_mfma_f32_32x32x16_bf16(af, bfr, acc[t], 0, 0, 0);
      }
    }
    __syncthreads();
  }

  // epilogue: bias, LayerNorm over 256 cols, gamma/beta, ReLU
  float bcol[8], gc[8], bc[8];
#pragma unroll
  for (int t = 0; t < 8; ++t) {
    int col = t * 32 + l31;
    bcol[t] = h_bias[col];
    gc[t] = gamma[col];
    bc[t] = beta[col];
  }
#pragma unroll
  for (int t = 0; t < 8; ++t)
#pragma unroll
    for (int r = 0; r < 16; ++r) acc[t][r] += bcol[t];

  const int m_base = m0 + wave * 32;
#pragma unroll
  for (int r = 0; r < 16; ++r) {
    float s = 0.f, q = 0.f;
#pragma unroll
    for (int t = 0; t < 8; ++t) { float v = acc[t][r]; s += v; q += v * v; }
#pragma unroll
    for (int m = 16; m >= 1; m >>= 1) {
      s += __shfl_xor(s, m);
      q += __shfl_xor(q, m);
    }
    float mean = s * (1.0f / 256.0f);
    float var = q * (1.0f / 256.0f) - mean * mean;
    float rstd = rsqrtf(var + 1e-5f);
    int row = (r & 3) + ((r >> 2) << 3) + (half << 2);  // C/D layout, 32x32
    int grow = m_base + row;
    if (grow < NN) {
#pragma unroll
      for (int t = 0; t < 8; ++t) {
        float v = (acc[t][r] - mean) * rstd * gc[t] + bc[t];
        out[(size_t)grow * 256 + t * 32 + l31] = fmaxf(v, 0.0f);
      }
    }
  }
}

extern "C" void kernel_launch(void* const* d_in, const int* in_sizes, int n_in,
                              void* d_out, int out_size, void* d_ws, size_t ws_size,
                              hipStream_t stream) {
  const float* x      = (const float*)d_in[0];
  const int*   src    = (const int*)d_in[1];
  const int*   dst    = (const int*)d_in[2];
  const float* bases  = (const float*)d_in[3];
  const float* w_comp = (const float*)d_in[4];
  const float* loop_w = (const float*)d_in[5];
  const float* h_bias = (const float*)d_in[6];
  const float* gamma  = (const float*)d_in[7];
  const float* beta   = (const float*)d_in[8];
  float* out = (float*)d_out;

  char* ws = (char*)d_ws;
  unsigned short* A  = (unsigned short*)ws;                // 153,600,000 B
  unsigned short* Bt = (unsigned short*)(ws + 153600000);  //     393,216 B
  int* cnt     = (int*)(ws + 153993216);                   //     400,000 B
  int* edgebuf = (int*)(ws + 154393216);                   //  25,600,000 B
  // total 179,993,216 B

  hipMemsetAsync(cnt, 0, 400000, stream);

  build_edges<<<(NR * NE + 255) / 256, 256, 0, stream>>>(src, dst, cnt, edgebuf);
  build_bt<<<768, 256, 0, stream>>>(bases, loop_w, Bt);
  conv_x<<<25000, 256, 0, stream>>>(x, A);
  agg_edges<<<25000, 256, 0, stream>>>(edgebuf, cnt, w_comp, A);
  gemm_ln<<<(NN + BM - 1) / BM, 256, 0, stream>>>(A, Bt, h_bias, gamma, beta, out);
}